// Round 14
// baseline (69.197 us; speedup 1.0000x reference)
//
#include <hip/hip_runtime.h>

#define TSTEPS 256
#define NOBJ   8192
#define BATCH  64
#define DEMB   32
#define DATT   128

// ws layout (bytes)
#define EX_OFF     0
#define SEGOFF_OFF 163840
#define EMB_OFF    172032
#define WS_NEED    (EMB_OFF + 5 * NOBJ * DEMB * 4)

struct SP {
    const float* x[5]; const int* cls[5]; const int* seg[5];
    const float* W[5]; const float* bias[5];
    const float* x_ped; const float* x_ego; const float* h_ped;
    const float* Wp; const float* bp; const float* We; const float* be;
    const float* Wax; const float* Wah; const float* ba; const float* va;
    const float* W1; const float* b1; const float* W2; const float* b2;
    const float* W3; const float* b3;
    const int* t_ptr;
    float* out;
    float* ex;      // [5][8192]
    int* seg_off;   // [5][65]
    float* emb;     // [5][8192][32]
    int d[5];
    int use_emb;
};

__device__ __forceinline__ int load_t(const void* p) {
    unsigned w0 = *(const unsigned*)p;
    if (w0 < (unsigned)TSTEPS) return (int)w0;
    float f = __uint_as_float(w0);
    if (f >= 0.f && f < 256.f) return (int)f;
    return 8;
}

__device__ __forceinline__ float fast_tanh(float x) {
    float e = __expf(2.0f * x);
    return 1.0f - 2.0f / (e + 1.0f);
}

// ---- kernel 1: 16 lanes/object, 2 objects/thread, 32 obj/block (R8 main loop).
// Absorbs k_prep: seg_off scatter for own window; hWl rows staged in the ONE
// existing staging phase (common span<=16; rare wider spans via uniform loop).
#define HWROWS 16
template<int D>
__device__ __forceinline__ void score_tile(const SP& p, const int type, const int blk,
                                           const int t, float* WaxT, float* W_s,
                                           float* b_s, float* hWl) {
    const int tid = threadIdx.x;
    const float* __restrict__ x   = p.x[type];
    const int*   __restrict__ cls = p.cls[type];
    const int*   __restrict__ seg = p.seg[type];

    const int q = tid & 15;     // j-slice lane (16 per object)
    const int o = tid >> 4;     // object slot 0..15
    const int i0 = blk * 32 + o;
    const int i1 = i0 + 16;

    // seg_off boundary scatter for this block's 32-object window
    if (tid < 32) {
        const int i  = blk * 32 + tid;
        const int sv = seg[i];
        const int pv = (i == 0) ? -1 : seg[i - 1];
        for (int v = pv + 1; v <= sv; ++v) p.seg_off[type * 65 + v] = i;
        if (i == NOBJ - 1)
            for (int v = sv + 1; v <= BATCH; ++v) p.seg_off[type * 65 + v] = NOBJ;
    }

    // issue all gathers early; latency overlaps LDS staging
    const int sfirst = seg[blk * 32];
    const int slast  = seg[blk * 32 + 31];
    const int c0 = cls[i0 * TSTEPS + t];
    const int c1 = cls[i1 * TSTEPS + t];
    const int b0 = seg[i0];
    const int b1 = seg[i1];
    float xv0[D], xv1[D];
    {
        const float* xr0 = x + (size_t)(i0 * TSTEPS + t) * D;
        const float* xr1 = x + (size_t)(i1 * TSTEPS + t) * D;
        #pragma unroll
        for (int k = 0; k < D; ++k) { xv0[k] = xr0[k]; xv1[k] = xr1[k]; }
    }
    float vv[8];
    *(float4*)(vv)     = *(const float4*)(p.va + q * 8);
    *(float4*)(vv + 4) = *(const float4*)(p.va + q * 8 + 4);

    // ---- staging phase (single __syncthreads) ----
    // Wax^T: linear LDS writes (conflict-free), transposed gather global-side
    for (int i = tid; i < DATT * DEMB; i += 256) {
        const int j = i >> 5, k = i & 31;
        WaxT[i] = p.Wax[k * DATT + j];
    }
    for (int i = tid; i < D * DEMB; i += 256) W_s[i] = p.W[type][i];
    if (tid < DEMB) b_s[tid] = p.bias[type][tid];
    // hW rows for this block's span (common: 1-2 rows -> ~1 element/thread)
    const int span  = slast - sfirst + 1;
    const int rows0 = min(span, HWROWS);
    for (int e = tid; e < rows0 * DATT; e += 256) {
        const int r = e >> 7, j = e & 127;
        float a = p.ba[j];
        const float* h = p.h_ped + (sfirst + r) * DEMB;
        #pragma unroll
        for (int k = 0; k < DEMB; ++k) a += h[k] * p.Wah[k * DATT + j];
        hWl[e] = a;                       // coalesced Wah reads, linear LDS write
    }
    __syncthreads();

    float acc0[8], acc1[8];
    #pragma unroll
    for (int jo = 0; jo < 8; ++jo) { acc0[jo] = 0.f; acc1[jo] = 0.f; }

    const float4* b4 = (const float4*)b_s;
    #pragma unroll
    for (int cc = 0; cc < 8; ++cc) {
        const int c = (cc + q) & 7;          // bank-group 4c: 2-way across lanes (free)
        float4 a0 = b4[c], a1 = b4[c];
        #pragma unroll
        for (int k = 0; k < D; ++k) {
            const float4 w = *(const float4*)&W_s[k * DEMB + 4 * c];
            a0.x += xv0[k]*w.x; a0.y += xv0[k]*w.y; a0.z += xv0[k]*w.z; a0.w += xv0[k]*w.w;
            a1.x += xv1[k]*w.x; a1.y += xv1[k]*w.y; a1.z += xv1[k]*w.z; a1.w += xv1[k]*w.w;
        }
        a0.x = fmaxf(a0.x, 0.f); a0.y = fmaxf(a0.y, 0.f);
        a0.z = fmaxf(a0.z, 0.f); a0.w = fmaxf(a0.w, 0.f);
        a1.x = fmaxf(a1.x, 0.f); a1.y = fmaxf(a1.y, 0.f);
        a1.z = fmaxf(a1.z, 0.f); a1.w = fmaxf(a1.w, 0.f);

        if (p.use_emb && cc == 0 && q < 8) {   // chunk q: write once
            *(float4*)&p.emb[((size_t)type * NOBJ + i0) * DEMB + 4 * q] = a0;
            *(float4*)&p.emb[((size_t)type * NOBJ + i1) * DEMB + 4 * q] = a1;
        }
        #pragma unroll
        for (int jo = 0; jo < 8; ++jo) {
            const float4 w = *(const float4*)&WaxT[(q * 8 + jo) * DEMB + 4 * c];
            acc0[jo] += a0.x*w.x + a0.y*w.y + a0.z*w.z + a0.w*w.w;
            acc1[jo] += a1.x*w.x + a1.y*w.y + a1.z*w.z + a1.w*w.w;
        }
    }

    // epilogue pass 0 (no extra sync): objects whose row is in [0, rows0)
    float sc0 = 0.f, sc1 = 0.f;
    const int r0 = b0 - sfirst;
    const int r1 = b1 - sfirst;
    if (r0 < rows0) {
        float hv[8];
        *(float4*)(hv)     = *(const float4*)&hWl[r0 * DATT + q * 8];
        *(float4*)(hv + 4) = *(const float4*)&hWl[r0 * DATT + q * 8 + 4];
        #pragma unroll
        for (int jo = 0; jo < 8; ++jo) sc0 += fast_tanh(hv[jo] + acc0[jo]) * vv[jo];
    }
    if (r1 < rows0) {
        float hv[8];
        *(float4*)(hv)     = *(const float4*)&hWl[r1 * DATT + q * 8];
        *(float4*)(hv + 4) = *(const float4*)&hWl[r1 * DATT + q * 8 + 4];
        #pragma unroll
        for (int jo = 0; jo < 8; ++jo) sc1 += fast_tanh(hv[jo] + acc1[jo]) * vv[jo];
    }
    // rare wide-span passes (block-uniform; never taken when span<=16)
    for (int base = HWROWS; base < span; base += HWROWS) {
        const int rows = min(span - base, HWROWS);
        __syncthreads();
        for (int e = tid; e < rows * DATT; e += 256) {
            const int r = e >> 7, j = e & 127;
            float a = p.ba[j];
            const float* h = p.h_ped + (sfirst + base + r) * DEMB;
            #pragma unroll
            for (int k = 0; k < DEMB; ++k) a += h[k] * p.Wah[k * DATT + j];
            hWl[e] = a;
        }
        __syncthreads();
        const int u0 = r0 - base, u1 = r1 - base;
        if (u0 >= 0 && u0 < rows) {
            float hv[8];
            *(float4*)(hv)     = *(const float4*)&hWl[u0 * DATT + q * 8];
            *(float4*)(hv + 4) = *(const float4*)&hWl[u0 * DATT + q * 8 + 4];
            #pragma unroll
            for (int jo = 0; jo < 8; ++jo) sc0 += fast_tanh(hv[jo] + acc0[jo]) * vv[jo];
        }
        if (u1 >= 0 && u1 < rows) {
            float hv[8];
            *(float4*)(hv)     = *(const float4*)&hWl[u1 * DATT + q * 8];
            *(float4*)(hv + 4) = *(const float4*)&hWl[u1 * DATT + q * 8 + 4];
            #pragma unroll
            for (int jo = 0; jo < 8; ++jo) sc1 += fast_tanh(hv[jo] + acc1[jo]) * vv[jo];
        }
    }

    sc0 += __shfl_xor(sc0, 1); sc1 += __shfl_xor(sc1, 1);
    sc0 += __shfl_xor(sc0, 2); sc1 += __shfl_xor(sc1, 2);
    sc0 += __shfl_xor(sc0, 4); sc1 += __shfl_xor(sc1, 4);
    sc0 += __shfl_xor(sc0, 8); sc1 += __shfl_xor(sc1, 8);

    if (q == 0) {
        p.ex[type * NOBJ + i0] = (c0 != -1) ? __expf(sc0) : 0.f;
        p.ex[type * NOBJ + i1] = (c1 != -1) ? __expf(sc1) : 0.f;
    }
}

__global__ __launch_bounds__(256) void k_score(SP p) {
    __shared__ __align__(16) float WaxT[DATT * DEMB];    // 16 KB
    __shared__ __align__(16) float W_s[7 * DEMB];
    __shared__ __align__(16) float b_s[DEMB];
    __shared__ __align__(16) float hWl[HWROWS * DATT];   // 8 KB
    const int t = load_t(p.t_ptr);
    switch (blockIdx.y) {
        case 0: score_tile<4>(p, 0, blockIdx.x, t, WaxT, W_s, b_s, hWl); break;
        case 1: score_tile<6>(p, 1, blockIdx.x, t, WaxT, W_s, b_s, hWl); break;
        case 2: score_tile<5>(p, 2, blockIdx.x, t, WaxT, W_s, b_s, hWl); break;
        case 3: score_tile<7>(p, 3, blockIdx.x, t, WaxT, W_s, b_s, hWl); break;
        default: score_tile<7>(p, 4, blockIdx.x, t, WaxT, W_s, b_s, hWl); break;
    }
}

// ---- kernel 2: per (type,segment) block: denom + probs + feature sum (R8 verbatim)
__global__ __launch_bounds__(256) void k_finish(SP p) {
    const int type = blockIdx.y;
    const int bseg = blockIdx.x;
    const int tid  = threadIdx.x;
    const int j    = tid & 31;
    const int sl   = tid >> 5;
    const int wv   = tid >> 6;
    const float* __restrict__ ex = p.ex + type * NOBJ;
    const int lo = p.seg_off[type * 65 + bseg];
    const int hi = p.seg_off[type * 65 + bseg + 1];

    __shared__ float red4[4];
    __shared__ float ared[4][DEMB];

    float s = 0.f;
    for (int i = lo + tid; i < hi; i += 256) s += ex[i];
    #pragma unroll
    for (int off = 32; off; off >>= 1) s += __shfl_xor(s, off);
    if ((tid & 63) == 0) red4[wv] = s;
    __syncthreads();
    const float inv = 1.0f / fmaxf(red4[0] + red4[1] + red4[2] + red4[3], 1e-30f);

    float acc = 0.f;
    float* pout = p.out + 64 + BATCH * 224 + type * NOBJ;
    if (p.use_emb) {
        const float* __restrict__ eb = p.emb + (size_t)type * NOBJ * DEMB;
        for (int i = lo + sl; i < hi; i += 8) {
            const float pr = ex[i] * inv;
            if (j == 0) pout[i] = pr;
            acc += pr * eb[(size_t)i * DEMB + j];   // 128B coalesced per slot
        }
    } else {
        const int t = load_t(p.t_ptr);
        const int d = p.d[type];
        float wj[7];
        for (int k = 0; k < d; ++k) wj[k] = p.W[type][k * DEMB + j];
        const float bj = p.bias[type][j];
        for (int i = lo + sl; i < hi; i += 8) {
            const float e = ex[i];
            const float pr = e * inv;
            if (j == 0) pout[i] = pr;
            if (e > 0.f) {
                const float* xr = p.x[type] + (size_t)(i * TSTEPS + t) * d;
                float a = bj;
                for (int k = 0; k < d; ++k) a += xr[k] * wj[k];
                acc += pr * fmaxf(a, 0.f);
            }
        }
    }
    acc += __shfl_xor(acc, 32);
    __syncthreads();
    if ((tid & 63) < 32) ared[wv][j] = acc;
    __syncthreads();
    if (tid < DEMB) {
        const float f = ared[0][tid] + ared[1][tid] + ared[2][tid] + ared[3][tid];
        p.out[64 + bseg * 224 + 32 * (1 + type) + tid] = f;
    }
}

// ---- kernel 3: classifier head (+ ped/ego embeddings), one block per batch row
__global__ __launch_bounds__(256) void k_head(SP p) {
    const int b   = blockIdx.x;
    const int tid = threadIdx.x;
    const int j   = tid & 31;
    const int sl  = tid >> 5;
    const int wv  = tid >> 6;
    __shared__ float feats_s[224];
    __shared__ float ared[4][DEMB];
    __shared__ float h1s[DEMB], h2s[DEMB];

    // ped (cols 0..31) / ego (cols 192..223)
    if (tid < 64) {
        const int t = load_t(p.t_ptr);
        const bool ego = tid >= 32;
        const float* xr = (ego ? p.x_ego : p.x_ped) + (size_t)(b * TSTEPS + t) * 4;
        const float* W  = ego ? p.We : p.Wp;
        const float* bb = ego ? p.be : p.bp;
        float a = bb[j];
        #pragma unroll
        for (int k = 0; k < 4; ++k) a += xr[k] * W[k * DEMB + j];
        a = fmaxf(a, 0.f);
        const int col = ego ? 192 + j : j;
        feats_s[col] = a;
        p.out[64 + b * 224 + col] = a;
    }
    if (tid >= 32 && tid < 192) feats_s[tid] = p.out[64 + b * 224 + tid];
    __syncthreads();

    float a1 = 0.f;
    const int k0 = sl * 28;
    #pragma unroll 4
    for (int k = k0; k < k0 + 28; ++k)
        a1 += feats_s[k] * p.W1[k * DEMB + j];
    a1 += __shfl_xor(a1, 32);
    if ((tid & 63) < 32) ared[wv][j] = a1;
    __syncthreads();
    if (tid < DEMB)
        h1s[tid] = fmaxf(ared[0][tid] + ared[1][tid] + ared[2][tid] + ared[3][tid] + p.b1[tid], 0.f);
    __syncthreads();
    if (tid < DEMB) {
        float a2 = p.b2[tid];
        #pragma unroll
        for (int k = 0; k < DEMB; ++k) a2 += h1s[k] * p.W2[k * DEMB + tid];
        h2s[tid] = fmaxf(a2, 0.f);
    }
    __syncthreads();
    if (tid < DEMB) {
        float v = h2s[tid] * p.W3[tid];
        v += __shfl_xor(v, 16); v += __shfl_xor(v, 8);
        v += __shfl_xor(v, 4);  v += __shfl_xor(v, 2); v += __shfl_xor(v, 1);
        if (tid == 0) p.out[b] = v + p.b3[0];
    }
}

extern "C" void kernel_launch(void* const* d_in, const int* in_sizes, int n_in,
                              void* d_out, int out_size, void* d_ws, size_t ws_size,
                              hipStream_t stream) {
    (void)in_sizes; (void)n_in; (void)out_size;

    SP p;
    const int xi[5] = {3, 6, 9, 12, 15};
    const int wi[5] = {20, 22, 24, 26, 28};
    const int di[5] = {4, 6, 5, 7, 7};
    for (int tp = 0; tp < 5; ++tp) {
        p.x[tp]    = (const float*)d_in[xi[tp]];
        p.cls[tp]  = (const int*)d_in[xi[tp] + 1];
        p.seg[tp]  = (const int*)d_in[xi[tp] + 2];
        p.W[tp]    = (const float*)d_in[wi[tp]];
        p.bias[tp] = (const float*)d_in[wi[tp] + 1];
        p.d[tp]    = di[tp];
    }
    p.x_ped = (const float*)d_in[0];
    p.x_ego = (const float*)d_in[1];
    p.h_ped = (const float*)d_in[2];
    p.Wp = (const float*)d_in[18]; p.bp = (const float*)d_in[19];
    p.We = (const float*)d_in[30]; p.be = (const float*)d_in[31];
    p.Wax = (const float*)d_in[32]; p.Wah = (const float*)d_in[33];
    p.ba  = (const float*)d_in[34]; p.va  = (const float*)d_in[35];
    p.W1 = (const float*)d_in[36]; p.b1 = (const float*)d_in[37];
    p.W2 = (const float*)d_in[38]; p.b2 = (const float*)d_in[39];
    p.W3 = (const float*)d_in[40]; p.b3 = (const float*)d_in[41];
    p.t_ptr = (const int*)d_in[42];
    p.out = (float*)d_out;
    char* ws = (char*)d_ws;
    p.ex      = (float*)(ws + EX_OFF);
    p.seg_off = (int*)(ws + SEGOFF_OFF);
    p.emb     = (float*)(ws + EMB_OFF);
    p.use_emb = (ws_size >= (size_t)WS_NEED) ? 1 : 0;

    hipLaunchKernelGGL(k_score,  dim3(NOBJ / 32, 5), dim3(256), 0, stream, p);
    hipLaunchKernelGGL(k_finish, dim3(BATCH, 5),     dim3(256), 0, stream, p);
    hipLaunchKernelGGL(k_head,   dim3(BATCH),        dim3(256), 0, stream, p);
}

// Round 15
// 45.010 us; speedup vs baseline: 1.5374x; 1.5374x over previous
//
#include <hip/hip_runtime.h>

#define TSTEPS 256
#define NOBJ   8192
#define BATCH  64
#define DEMB   32
#define DATT   128

// ws layout (bytes)
#define HW_OFF     0
#define EX_OFF     32768
#define SEGOFF_OFF 196608
#define EMB_OFF    199168
#define WS_NEED    (EMB_OFF + 5 * NOBJ * DEMB * 4)

struct SP {
    const float* x[5]; const int* cls[5]; const int* seg[5];
    const float* W[5]; const float* bias[5];
    const float* x_ped; const float* x_ego; const float* h_ped;
    const float* Wp; const float* bp; const float* We; const float* be;
    const float* Wax; const float* Wah; const float* ba; const float* va;
    const float* W1; const float* b1; const float* W2; const float* b2;
    const float* W3; const float* b3;
    const int* t_ptr;
    float* out;
    float* hW;      // [64][128]
    float* ex;      // [5][8192]
    int* seg_off;   // [5][65]
    float* emb;     // [5][8192][32]
    int d[5];
    int use_emb;
};

__device__ __forceinline__ int load_t(const void* p) {
    unsigned w0 = *(const unsigned*)p;
    if (w0 < (unsigned)TSTEPS) return (int)w0;
    float f = __uint_as_float(w0);
    if (f >= 0.f && f < 256.f) return (int)f;
    return 8;
}

__device__ __forceinline__ float fast_tanh(float x) {
    float e = __expf(2.0f * x);
    return 1.0f - 2.0f / (e + 1.0f);
}

// ---- kernel 0: hW + ped/ego feats (blocks 0..63); seg_off scatter (blocks 64..223)
__global__ __launch_bounds__(256) void k_prep(SP p) {
    if (blockIdx.x >= BATCH) {
        const int g    = (blockIdx.x - BATCH) * 256 + threadIdx.x;   // 160*256 = 40960
        const int type = g >> 13;
        const int i    = g & (NOBJ - 1);
        const int* __restrict__ seg = p.seg[type];
        const int sv = seg[i];
        const int pv = (i == 0) ? -1 : seg[i - 1];
        for (int v = pv + 1; v <= sv; ++v) p.seg_off[type * 65 + v] = i;
        if (i == NOBJ - 1)
            for (int v = sv + 1; v <= BATCH; ++v) p.seg_off[type * 65 + v] = NOBJ;
        return;
    }
    const int b = blockIdx.x;
    const int j = threadIdx.x;
    const int t = load_t(p.t_ptr);
    if (j < DATT) {
        float a = p.ba[j];
        const float* h = p.h_ped + b * DEMB;
        #pragma unroll
        for (int k = 0; k < DEMB; ++k) a += h[k] * p.Wah[k * DATT + j];
        p.hW[b * DATT + j] = a;
    }
    if (j < DEMB) {
        const float* xp = p.x_ped + (size_t)(b * TSTEPS + t) * 4;
        float e = p.bp[j];
        #pragma unroll
        for (int k = 0; k < 4; ++k) e += xp[k] * p.Wp[k * DEMB + j];
        p.out[64 + b * 224 + j] = fmaxf(e, 0.f);
        const float* xe = p.x_ego + (size_t)(b * TSTEPS + t) * 4;
        float g = p.be[j];
        #pragma unroll
        for (int k = 0; k < 4; ++k) g += xe[k] * p.We[k * DEMB + j];
        p.out[64 + b * 224 + 192 + j] = fmaxf(g, 0.f);
    }
}

// ---- kernel 1: 16 lanes/object, 2 objects/thread, 32 obj/block (R8-proven).
// Inverted loops: tanh-arg accumulators acc[8] live; emb computed chunk-by-chunk.
template<int D>
__device__ __forceinline__ void score_body(const SP& p, const int type, const int t,
                                           float* WaxT, float* W_s, float* b_s) {
    const int tid = threadIdx.x;
    const float* __restrict__ x   = p.x[type];
    const int*   __restrict__ cls = p.cls[type];
    const int*   __restrict__ seg = p.seg[type];

    const int q = tid & 15;     // j-slice lane (16 per object)
    const int o = tid >> 4;     // object slot 0..15
    const int i0 = blockIdx.x * 32 + o;
    const int i1 = i0 + 16;

    // issue all gathers early; latency overlaps LDS staging
    const int c0 = cls[i0 * TSTEPS + t];
    const int c1 = cls[i1 * TSTEPS + t];
    const int b0 = seg[i0];
    const int b1 = seg[i1];
    float xv0[D], xv1[D];
    {
        const float* xr0 = x + (size_t)(i0 * TSTEPS + t) * D;
        const float* xr1 = x + (size_t)(i1 * TSTEPS + t) * D;
        #pragma unroll
        for (int k = 0; k < D; ++k) { xv0[k] = xr0[k]; xv1[k] = xr1[k]; }
    }
    // per-lane j-slice operands (prefetch; consumed in epilogue)
    float hv0[8], hv1[8], vv[8];
    {
        const float* hp0 = p.hW + b0 * DATT + q * 8;
        const float* hp1 = p.hW + b1 * DATT + q * 8;
        const float* vp  = p.va + q * 8;
        *(float4*)(hv0)   = *(const float4*)(hp0);
        *(float4*)(hv0+4) = *(const float4*)(hp0+4);
        *(float4*)(hv1)   = *(const float4*)(hp1);
        *(float4*)(hv1+4) = *(const float4*)(hp1+4);
        *(float4*)(vv)    = *(const float4*)(vp);
        *(float4*)(vv+4)  = *(const float4*)(vp+4);
    }

    // stage Wax^T: linear LDS writes (conflict-free), transposed gather global-side
    for (int i = tid; i < DATT * DEMB; i += 256) {
        const int j = i >> 5, k = i & 31;
        WaxT[i] = p.Wax[k * DATT + j];
    }
    for (int i = tid; i < D * DEMB; i += 256) W_s[i] = p.W[type][i];
    if (tid < DEMB) b_s[tid] = p.bias[type][tid];
    __syncthreads();

    float acc0[8], acc1[8];
    #pragma unroll
    for (int jo = 0; jo < 8; ++jo) { acc0[jo] = 0.f; acc1[jo] = 0.f; }

    const float4* b4 = (const float4*)b_s;
    #pragma unroll
    for (int cc = 0; cc < 8; ++cc) {
        const int c = (cc + q) & 7;          // bank-group 4c: 2-way across lanes (free)
        // emb chunk c for both objects
        float4 a0 = b4[c], a1 = b4[c];
        #pragma unroll
        for (int k = 0; k < D; ++k) {
            const float4 w = *(const float4*)&W_s[k * DEMB + 4 * c];
            a0.x += xv0[k]*w.x; a0.y += xv0[k]*w.y; a0.z += xv0[k]*w.z; a0.w += xv0[k]*w.w;
            a1.x += xv1[k]*w.x; a1.y += xv1[k]*w.y; a1.z += xv1[k]*w.z; a1.w += xv1[k]*w.w;
        }
        a0.x = fmaxf(a0.x, 0.f); a0.y = fmaxf(a0.y, 0.f);
        a0.z = fmaxf(a0.z, 0.f); a0.w = fmaxf(a0.w, 0.f);
        a1.x = fmaxf(a1.x, 0.f); a1.y = fmaxf(a1.y, 0.f);
        a1.z = fmaxf(a1.z, 0.f); a1.w = fmaxf(a1.w, 0.f);

        if (p.use_emb && cc == 0 && q < 8) {   // chunk q: write once
            *(float4*)&p.emb[((size_t)type * NOBJ + i0) * DEMB + 4 * q] = a0;
            *(float4*)&p.emb[((size_t)type * NOBJ + i1) * DEMB + 4 * q] = a1;
        }
        #pragma unroll
        for (int jo = 0; jo < 8; ++jo) {
            const float4 w = *(const float4*)&WaxT[(q * 8 + jo) * DEMB + 4 * c];
            acc0[jo] += a0.x*w.x + a0.y*w.y + a0.z*w.z + a0.w*w.w;
            acc1[jo] += a1.x*w.x + a1.y*w.y + a1.z*w.z + a1.w*w.w;
        }
    }

    float sc0 = 0.f, sc1 = 0.f;
    #pragma unroll
    for (int jo = 0; jo < 8; ++jo) {
        sc0 += fast_tanh(hv0[jo] + acc0[jo]) * vv[jo];
        sc1 += fast_tanh(hv1[jo] + acc1[jo]) * vv[jo];
    }
    sc0 += __shfl_xor(sc0, 1); sc1 += __shfl_xor(sc1, 1);
    sc0 += __shfl_xor(sc0, 2); sc1 += __shfl_xor(sc1, 2);
    sc0 += __shfl_xor(sc0, 4); sc1 += __shfl_xor(sc1, 4);
    sc0 += __shfl_xor(sc0, 8); sc1 += __shfl_xor(sc1, 8);

    if (q == 0) {
        p.ex[type * NOBJ + i0] = (c0 != -1) ? __expf(sc0) : 0.f;
        p.ex[type * NOBJ + i1] = (c1 != -1) ? __expf(sc1) : 0.f;
    }
}

__global__ __launch_bounds__(256) void k_score(SP p) {
    __shared__ __align__(16) float WaxT[DATT * DEMB];   // 16 KB
    __shared__ __align__(16) float W_s[7 * DEMB];
    __shared__ __align__(16) float b_s[DEMB];
    const int t = load_t(p.t_ptr);
    switch (blockIdx.y) {
        case 0: score_body<4>(p, 0, t, WaxT, W_s, b_s); break;
        case 1: score_body<6>(p, 1, t, WaxT, W_s, b_s); break;
        case 2: score_body<5>(p, 2, t, WaxT, W_s, b_s); break;
        case 3: score_body<7>(p, 3, t, WaxT, W_s, b_s); break;
        default: score_body<7>(p, 4, t, WaxT, W_s, b_s); break;
    }
}

// ---- kernel 2: per (type,segment) block: denom + probs + feature sum
__global__ __launch_bounds__(256) void k_finish(SP p) {
    const int type = blockIdx.y;
    const int bseg = blockIdx.x;
    const int tid  = threadIdx.x;
    const int j    = tid & 31;
    const int sl   = tid >> 5;   // 0..7 object slot
    const int wv   = tid >> 6;
    const float* __restrict__ ex = p.ex + type * NOBJ;
    const int lo = p.seg_off[type * 65 + bseg];
    const int hi = p.seg_off[type * 65 + bseg + 1];

    __shared__ float red4[4];
    __shared__ float ared[4][DEMB];

    float s = 0.f;
    for (int i = lo + tid; i < hi; i += 256) s += ex[i];
    #pragma unroll
    for (int off = 32; off; off >>= 1) s += __shfl_xor(s, off);
    if ((tid & 63) == 0) red4[wv] = s;
    __syncthreads();
    const float inv = 1.0f / fmaxf(red4[0] + red4[1] + red4[2] + red4[3], 1e-30f);

    float acc = 0.f;
    float* pout = p.out + 64 + BATCH * 224 + type * NOBJ;
    if (p.use_emb) {
        const float* __restrict__ eb = p.emb + (size_t)type * NOBJ * DEMB;
        for (int i = lo + sl; i < hi; i += 8) {
            const float pr = ex[i] * inv;
            if (j == 0) pout[i] = pr;
            acc += pr * eb[(size_t)i * DEMB + j];   // 128B coalesced per slot
        }
    } else {
        const int t = load_t(p.t_ptr);
        const int d = p.d[type];
        float wj[7];
        for (int k = 0; k < d; ++k) wj[k] = p.W[type][k * DEMB + j];
        const float bj = p.bias[type][j];
        for (int i = lo + sl; i < hi; i += 8) {
            const float e = ex[i];
            const float pr = e * inv;
            if (j == 0) pout[i] = pr;
            if (e > 0.f) {
                const float* xr = p.x[type] + (size_t)(i * TSTEPS + t) * d;
                float a = bj;
                for (int k = 0; k < d; ++k) a += xr[k] * wj[k];
                acc += pr * fmaxf(a, 0.f);
            }
        }
    }
    acc += __shfl_xor(acc, 32);    // merge slot pairs within wave
    if ((tid & 63) < 32) ared[wv][j] = acc;
    __syncthreads();
    if (tid < DEMB) {
        const float f = ared[0][tid] + ared[1][tid] + ared[2][tid] + ared[3][tid];
        p.out[64 + bseg * 224 + 32 * (1 + type) + tid] = f;
    }
}

// ---- kernel 3: classifier head, one wave per batch row
__global__ __launch_bounds__(64) void k_head(SP p) {
    const int b   = blockIdx.x;
    const int tid = threadIdx.x;
    const int j    = tid & 31;
    const int half = tid >> 5;
    __shared__ float h1s[DEMB];
    __shared__ float h2s[DEMB];
    const float* feats = p.out + 64 + b * 224;

    float a = 0.f;
    const int k0 = half * 112;
    #pragma unroll 4
    for (int k = k0; k < k0 + 112; ++k)
        a += feats[k] * p.W1[k * DEMB + j];
    a += __shfl_xor(a, 32);
    if (half == 0) h1s[j] = fmaxf(a + p.b1[j], 0.f);
    __syncthreads();

    float a2 = 0.f;
    const int k2 = half * 16;
    #pragma unroll
    for (int k = k2; k < k2 + 16; ++k)
        a2 += h1s[k] * p.W2[k * DEMB + j];
    a2 += __shfl_xor(a2, 32);
    if (half == 0) h2s[j] = fmaxf(a2 + p.b2[j], 0.f);
    __syncthreads();

    if (half == 0) {
        float v = h2s[j] * p.W3[j];
        v += __shfl_xor(v, 16); v += __shfl_xor(v, 8);
        v += __shfl_xor(v, 4);  v += __shfl_xor(v, 2); v += __shfl_xor(v, 1);
        if (j == 0) p.out[b] = v + p.b3[0];
    }
}

extern "C" void kernel_launch(void* const* d_in, const int* in_sizes, int n_in,
                              void* d_out, int out_size, void* d_ws, size_t ws_size,
                              hipStream_t stream) {
    (void)in_sizes; (void)n_in; (void)out_size;

    SP p;
    const int xi[5] = {3, 6, 9, 12, 15};
    const int wi[5] = {20, 22, 24, 26, 28};
    const int di[5] = {4, 6, 5, 7, 7};
    for (int tp = 0; tp < 5; ++tp) {
        p.x[tp]    = (const float*)d_in[xi[tp]];
        p.cls[tp]  = (const int*)d_in[xi[tp] + 1];
        p.seg[tp]  = (const int*)d_in[xi[tp] + 2];
        p.W[tp]    = (const float*)d_in[wi[tp]];
        p.bias[tp] = (const float*)d_in[wi[tp] + 1];
        p.d[tp]    = di[tp];
    }
    p.x_ped = (const float*)d_in[0];
    p.x_ego = (const float*)d_in[1];
    p.h_ped = (const float*)d_in[2];
    p.Wp = (const float*)d_in[18]; p.bp = (const float*)d_in[19];
    p.We = (const float*)d_in[30]; p.be = (const float*)d_in[31];
    p.Wax = (const float*)d_in[32]; p.Wah = (const float*)d_in[33];
    p.ba  = (const float*)d_in[34]; p.va  = (const float*)d_in[35];
    p.W1 = (const float*)d_in[36]; p.b1 = (const float*)d_in[37];
    p.W2 = (const float*)d_in[38]; p.b2 = (const float*)d_in[39];
    p.W3 = (const float*)d_in[40]; p.b3 = (const float*)d_in[41];
    p.t_ptr = (const int*)d_in[42];
    p.out = (float*)d_out;
    char* ws = (char*)d_ws;
    p.hW      = (float*)(ws + HW_OFF);
    p.ex      = (float*)(ws + EX_OFF);
    p.seg_off = (int*)(ws + SEGOFF_OFF);
    p.emb     = (float*)(ws + EMB_OFF);
    p.use_emb = (ws_size >= (size_t)WS_NEED) ? 1 : 0;

    hipLaunchKernelGGL(k_prep,   dim3(BATCH + 160),  dim3(256), 0, stream, p);
    hipLaunchKernelGGL(k_score,  dim3(NOBJ / 32, 5), dim3(256), 0, stream, p);
    hipLaunchKernelGGL(k_finish, dim3(BATCH, 5),     dim3(256), 0, stream, p);
    hipLaunchKernelGGL(k_head,   dim3(BATCH),        dim3(64),  0, stream, p);
}